// Round 1
// baseline (224.292 us; speedup 1.0000x reference)
//
#include <hip/hip_runtime.h>
#include <hip/hip_bf16.h>
#include <cstdint>

// MCSoftContrastiveLoss, MI355X (gfx950)
// loss = 2 * sum_{i,j} [ log(256) - log( sum_{k,l} sigmoid(2*m_ij*logit) ) ]
//   logit = shift - ns * sqrt(max(x2+y2-2xy,0)+1e-6),  m_ij = +1 if i==j else -1
// xy via bf16 hi/lo split (3 GEMMs) on MFMA; x2/y2 exact fp32.

using f32x4 = __attribute__((ext_vector_type(4))) float;
using s16x8 = __attribute__((ext_vector_type(8))) short;

#define NRROWS 4096
#define DDIM   1024
#define BM     128
#define BN     128
#define BK     64
#define LOGKK  5.5451774444795625f
#define DEPS   1e-6f

__device__ __forceinline__ void gload16(const void* g, void* l) {
  __builtin_amdgcn_global_load_lds((const __attribute__((address_space(1))) void*)g,
                                   (__attribute__((address_space(3))) void*)l, 16, 0, 0);
}

__device__ __forceinline__ unsigned short bf16_rne(float x) {
  uint32_t u = __builtin_bit_cast(uint32_t, x);
  uint32_t r = (u + 0x7FFFu + ((u >> 16) & 1u)) >> 16;
  return (unsigned short)r;
}
__device__ __forceinline__ float bf16_f(unsigned short h) {
  uint32_t u = ((uint32_t)h) << 16;
  return __builtin_bit_cast(float, u);
}

// ---------------- prep: hi/lo split + row sum-of-squares + zero out ----------------
__global__ __launch_bounds__(256) void mcsc_prep(
    const float* __restrict__ img, const float* __restrict__ cap,
    unsigned short* __restrict__ Xhi, unsigned short* __restrict__ Xlo,
    unsigned short* __restrict__ Yhi, unsigned short* __restrict__ Ylo,
    float* __restrict__ x2, float* __restrict__ y2, float* __restrict__ out)
{
  int b = blockIdx.x;             // 0..8191
  int isY = b >> 12;
  int row = b & 4095;
  const float* src = (isY ? cap : img) + (size_t)row * DDIM;
  unsigned short* hi = (isY ? Yhi : Xhi) + (size_t)row * DDIM;
  unsigned short* lo = (isY ? Ylo : Xlo) + (size_t)row * DDIM;

  int t = threadIdx.x;
  float4 v = *(const float4*)(src + t * 4);
  float s = 0.f;
  unsigned short h4[4], l4[4];
  const float* vp = (const float*)&v;
#pragma unroll
  for (int j = 0; j < 4; ++j) {
    float x = vp[j];
    s += x * x;
    unsigned short h = bf16_rne(x);
    float r = x - bf16_f(h);
    h4[j] = h;
    l4[j] = bf16_rne(r);
  }
  *(ushort4*)(hi + t * 4) = make_ushort4(h4[0], h4[1], h4[2], h4[3]);
  *(ushort4*)(lo + t * 4) = make_ushort4(l4[0], l4[1], l4[2], l4[3]);

#pragma unroll
  for (int off = 32; off >= 1; off >>= 1) s += __shfl_xor(s, off);
  __shared__ float wsum[4];
  if ((t & 63) == 0) wsum[t >> 6] = s;
  __syncthreads();
  if (t == 0) {
    (isY ? y2 : x2)[row] = wsum[0] + wsum[1] + wsum[2] + wsum[3];
    if (b == 0) out[0] = 0.f;
  }
}

// ---------------- main: 128x128 tile NT-GEMM + fused epilogue ----------------
__global__ __launch_bounds__(256, 2) void mcsc_main(
    const unsigned short* __restrict__ Xhi, const unsigned short* __restrict__ Xlo,
    const unsigned short* __restrict__ Yhi, const unsigned short* __restrict__ Ylo,
    const float* __restrict__ x2, const float* __restrict__ y2,
    const float* __restrict__ nsp, const float* __restrict__ shp,
    float* __restrict__ out)
{
  __shared__ __align__(16) char ldsA[BM * BK * 2];   // 16 KiB
  __shared__ __align__(16) char ldsB[BN * BK * 2];   // 16 KiB

  // XCD-bijective swizzle (1024 % 8 == 0)
  int bid = blockIdx.x;
  int wg = (bid & 7) * 128 + (bid >> 3);
  int bm = wg >> 5, bn = wg & 31;
  int rowBase = bm * BM, colBase = bn * BN;

  int t = threadIdx.x;
  int wid = t >> 6, lane = t & 63;
  int lr = lane & 15, lk = lane >> 4;
  int wr = wid >> 1, wc = wid & 1;
  int waveRow = wr * 64, waveCol = wc * 64;

  f32x4 acc[4][4] = {};

  // 3 K-segments of 1024: hiX.hiY + hiX.loY + loX.hiY
  for (int ks = 0; ks < 48; ++ks) {
    int seg = ks >> 4;
    int koff = (ks & 15) * BK;
    const unsigned short* Asrc = (seg < 2) ? Xhi : Xlo;
    const unsigned short* Bsrc = (seg == 0) ? Yhi : ((seg == 1) ? Ylo : Yhi);

    // stage: linear LDS dest, inverse-swizzled global source (rule #21)
#pragma unroll
    for (int c = 0; c < 4; ++c) {
      int q = c * 4096 + t * 16;               // physical LDS byte this thread fills
      int row = q >> 7;                        // 128 B per tile row
      int colb = (q ^ ((row & 7) << 4)) & 127; // logical column byte
      const char* gA = (const char*)(Asrc + (size_t)(rowBase + row) * DDIM + koff) + colb;
      const char* gB = (const char*)(Bsrc + (size_t)(colBase + row) * DDIM + koff) + colb;
      gload16(gA, ldsA + c * 4096 + wid * 1024);
      gload16(gB, ldsB + c * 4096 + wid * 1024);
    }
    __syncthreads();

#pragma unroll
    for (int kk = 0; kk < BK; kk += 32) {
      s16x8 af[4], bf[4];
#pragma unroll
      for (int m = 0; m < 4; ++m) {
        int rl = waveRow + m * 16 + lr;
        int addr = rl * 128 + ((((kk + lk * 8) * 2)) ^ ((rl & 7) << 4));
        af[m] = *(const s16x8*)(ldsA + addr);
      }
#pragma unroll
      for (int n = 0; n < 4; ++n) {
        int rl = waveCol + n * 16 + lr;
        int addr = rl * 128 + ((((kk + lk * 8) * 2)) ^ ((rl & 7) << 4));
        bf[n] = *(const s16x8*)(ldsB + addr);
      }
#pragma unroll
      for (int m = 0; m < 4; ++m)
#pragma unroll
        for (int n = 0; n < 4; ++n)
          acc[m][n] = __builtin_amdgcn_mfma_f32_16x16x32_bf16(af[m], bf[n], acc[m][n], 0, 0, 0);
    }
    __syncthreads();
  }

  // fused epilogue: each 16x16 C-fragment == one (i,j) pair block
  float ns = nsp[0], sh = shp[0];
  float waveAcc = 0.f;
#pragma unroll
  for (int m = 0; m < 4; ++m) {
    int gr0 = rowBase + waveRow + m * 16;
    f32x4 x2v = *(const f32x4*)(x2 + gr0 + lk * 4);   // rows lk*4..lk*4+3
#pragma unroll
    for (int n = 0; n < 4; ++n) {
      int gc0 = colBase + waveCol + n * 16;
      bool diag = ((gr0 >> 4) == (gc0 >> 4));
      float y2c = y2[gc0 + lr];                        // col = lane&15
      float ts = 0.f;
#pragma unroll
      for (int r = 0; r < 4; ++r) {
        float sq = x2v[r] + y2c - 2.f * acc[m][n][r];
        sq = fmaxf(sq, 0.f);
        float dd = __fsqrt_rn(sq + DEPS);
        float l = sh - ns * dd;
        float a = diag ? (2.f * l) : (-2.f * l);
        ts += 1.f / (1.f + __expf(-a));                // sigmoid(2*m*l)
      }
#pragma unroll
      for (int off = 32; off >= 1; off >>= 1) ts += __shfl_xor(ts, off);
      waveAcc += (LOGKK - __logf(ts));
    }
  }
  if (lane == 0) atomicAdd(out, 2.f * waveAcc);
}

// ---------------- launch ----------------
extern "C" void kernel_launch(void* const* d_in, const int* in_sizes, int n_in,
                              void* d_out, int out_size, void* d_ws, size_t ws_size,
                              hipStream_t stream) {
  const float* img = (const float*)d_in[0];
  const float* cap = (const float*)d_in[1];
  const float* nsp = (const float*)d_in[4];
  const float* shp = (const float*)d_in[5];
  float* out = (float*)d_out;

  char* ws = (char*)d_ws;
  unsigned short* Xhi = (unsigned short*)(ws + (size_t)0);
  unsigned short* Xlo = (unsigned short*)(ws + (size_t)8 * 1024 * 1024);
  unsigned short* Yhi = (unsigned short*)(ws + (size_t)16 * 1024 * 1024);
  unsigned short* Ylo = (unsigned short*)(ws + (size_t)24 * 1024 * 1024);
  float* x2 = (float*)(ws + (size_t)32 * 1024 * 1024);
  float* y2 = (float*)(ws + (size_t)32 * 1024 * 1024 + 16384);
  // ws needed: 32 MiB + 32 KiB

  mcsc_prep<<<dim3(8192), dim3(256), 0, stream>>>(img, cap, Xhi, Xlo, Yhi, Ylo, x2, y2, out);
  mcsc_main<<<dim3(1024), dim3(256), 0, stream>>>(Xhi, Xlo, Yhi, Ylo, x2, y2, nsp, shp, out);
}

// Round 4
// 169.146 us; speedup vs baseline: 1.3260x; 1.3260x over previous
//
#include <hip/hip_runtime.h>
#include <hip/hip_bf16.h>
#include <cstdint>

// MCSoftContrastiveLoss, MI355X (gfx950)
// loss = 2 * sum_{i,j} [ log(256) - log( sum_{k,l} sigmoid(2*m_ij*logit) ) ]
//   logit = shift - ns * sqrt(max(x2+y2-2xy,0)+1e-6),  m_ij = +1 if i==j else -1
// xy via single bf16 GEMM on MFMA (error ~5e-6 relative); x2/y2 exact fp32.

using f32x4 = __attribute__((ext_vector_type(4))) float;
using s16x8 = __attribute__((ext_vector_type(8))) short;

#define DDIM   1024
#define BM     128
#define BN     128
#define BK     64
#define LOGKK  5.5451774444795625f
#define DEPS   1e-6f

__device__ __forceinline__ void gload16(const void* g, void* l) {
  __builtin_amdgcn_global_load_lds((const __attribute__((address_space(1))) void*)g,
                                   (__attribute__((address_space(3))) void*)l, 16, 0, 0);
}

__device__ __forceinline__ unsigned short bf16_rne(float x) {
  uint32_t u = __builtin_bit_cast(uint32_t, x);
  uint32_t r = (u + 0x7FFFu + ((u >> 16) & 1u)) >> 16;
  return (unsigned short)r;
}

// ---------------- prep: bf16 round + row sum-of-squares + zero out ----------------
__global__ __launch_bounds__(256) void mcsc_prep(
    const float* __restrict__ img, const float* __restrict__ cap,
    unsigned short* __restrict__ Xhi, unsigned short* __restrict__ Yhi,
    float* __restrict__ x2, float* __restrict__ y2, float* __restrict__ out)
{
  int b = blockIdx.x;             // 0..8191
  int isY = b >> 12;
  int row = b & 4095;
  const float* src = (isY ? cap : img) + (size_t)row * DDIM;
  unsigned short* hi = (isY ? Yhi : Xhi) + (size_t)row * DDIM;

  int t = threadIdx.x;
  float4 v = *(const float4*)(src + t * 4);
  float s = 0.f;
  unsigned short h4[4];
  const float* vp = (const float*)&v;
#pragma unroll
  for (int j = 0; j < 4; ++j) {
    float x = vp[j];
    s += x * x;                       // exact fp32 norm (not bf16-rounded)
    h4[j] = bf16_rne(x);
  }
  *(ushort4*)(hi + t * 4) = make_ushort4(h4[0], h4[1], h4[2], h4[3]);

#pragma unroll
  for (int off = 32; off >= 1; off >>= 1) s += __shfl_xor(s, off);
  __shared__ float wsum[4];
  if ((t & 63) == 0) wsum[t >> 6] = s;
  __syncthreads();
  if (t == 0) {
    (isY ? y2 : x2)[row] = wsum[0] + wsum[1] + wsum[2] + wsum[3];
    if (b == 0) out[0] = 0.f;
  }
}

// ---------------- main: 128x128 tile NT-GEMM + fused epilogue ----------------
__global__ __launch_bounds__(256, 2) void mcsc_main(
    const unsigned short* __restrict__ Xhi, const unsigned short* __restrict__ Yhi,
    const float* __restrict__ x2, const float* __restrict__ y2,
    const float* __restrict__ nsp, const float* __restrict__ shp,
    float* __restrict__ out)
{
  __shared__ __align__(16) char ldsA[BM * BK * 2];   // 16 KiB
  __shared__ __align__(16) char ldsB[BN * BK * 2];   // 16 KiB

  // XCD-bijective swizzle (1024 % 8 == 0)
  int bid = blockIdx.x;
  int wg = (bid & 7) * 128 + (bid >> 3);
  int bm = wg >> 5, bn = wg & 31;
  int rowBase = bm * BM, colBase = bn * BN;

  int t = threadIdx.x;
  int wid = t >> 6, lane = t & 63;
  int lr = lane & 15, lk = lane >> 4;
  int wr = wid >> 1, wc = wid & 1;
  int waveRow = wr * 64, waveCol = wc * 64;

  f32x4 acc[4][4] = {};

  for (int ks = 0; ks < 16; ++ks) {
    int koff = ks * BK;

    // stage: linear LDS dest, inverse-swizzled global source (rule #21)
#pragma unroll
    for (int c = 0; c < 4; ++c) {
      int q = c * 4096 + t * 16;               // physical LDS byte this thread fills
      int row = q >> 7;                        // 128 B per tile row
      int colb = (q ^ ((row & 7) << 4)) & 127; // logical column byte
      const char* gA = (const char*)(Xhi + (size_t)(rowBase + row) * DDIM + koff) + colb;
      const char* gB = (const char*)(Yhi + (size_t)(colBase + row) * DDIM + koff) + colb;
      gload16(gA, ldsA + c * 4096 + wid * 1024);
      gload16(gB, ldsB + c * 4096 + wid * 1024);
    }
    __syncthreads();

#pragma unroll
    for (int kk = 0; kk < BK; kk += 32) {
      s16x8 af[4], bf[4];
#pragma unroll
      for (int m = 0; m < 4; ++m) {
        int rl = waveRow + m * 16 + lr;
        int addr = rl * 128 + ((((kk + lk * 8) * 2)) ^ ((rl & 7) << 4));
        af[m] = *(const s16x8*)(ldsA + addr);
      }
#pragma unroll
      for (int n = 0; n < 4; ++n) {
        int rl = waveCol + n * 16 + lr;
        int addr = rl * 128 + ((((kk + lk * 8) * 2)) ^ ((rl & 7) << 4));
        bf[n] = *(const s16x8*)(ldsB + addr);
      }
#pragma unroll
      for (int m = 0; m < 4; ++m)
#pragma unroll
        for (int n = 0; n < 4; ++n)
          acc[m][n] = __builtin_amdgcn_mfma_f32_16x16x32_bf16(af[m], bf[n], acc[m][n], 0, 0, 0);
    }
    __syncthreads();
  }

  // fused epilogue: each 16x16 C-fragment == one (i,j) pair block
  float ns = nsp[0], sh = shp[0];
  float waveAcc = 0.f;
#pragma unroll
  for (int m = 0; m < 4; ++m) {
    int gr0 = rowBase + waveRow + m * 16;
    f32x4 x2v = *(const f32x4*)(x2 + gr0 + lk * 4);   // rows lk*4..lk*4+3
#pragma unroll
    for (int n = 0; n < 4; ++n) {
      int gc0 = colBase + waveCol + n * 16;
      bool diag = ((gr0 >> 4) == (gc0 >> 4));
      float y2c = y2[gc0 + lr];                        // col = lane&15
      float ts = 0.f;
#pragma unroll
      for (int r = 0; r < 4; ++r) {
        float sq = x2v[r] + y2c - 2.f * acc[m][n][r];
        sq = fmaxf(sq, 0.f);
        float dd = __fsqrt_rn(sq + DEPS);
        float l = sh - ns * dd;
        float a = diag ? (2.f * l) : (-2.f * l);
        ts += 1.f / (1.f + __expf(-a));                // sigmoid(2*m*l)
      }
#pragma unroll
      for (int off = 32; off >= 1; off >>= 1) ts += __shfl_xor(ts, off);
      waveAcc += (LOGKK - __logf(ts));
    }
  }
  if (lane == 0) atomicAdd(out, 2.f * waveAcc);
}

// ---------------- launch ----------------
extern "C" void kernel_launch(void* const* d_in, const int* in_sizes, int n_in,
                              void* d_out, int out_size, void* d_ws, size_t ws_size,
                              hipStream_t stream) {
  const float* img = (const float*)d_in[0];
  const float* cap = (const float*)d_in[1];
  const float* nsp = (const float*)d_in[4];
  const float* shp = (const float*)d_in[5];
  float* out = (float*)d_out;

  char* ws = (char*)d_ws;
  unsigned short* Xhi = (unsigned short*)(ws + (size_t)0);
  unsigned short* Yhi = (unsigned short*)(ws + (size_t)8 * 1024 * 1024);
  float* x2 = (float*)(ws + (size_t)16 * 1024 * 1024);
  float* y2 = (float*)(ws + (size_t)16 * 1024 * 1024 + 16384);
  // ws needed: 16 MiB + 32 KiB

  mcsc_prep<<<dim3(8192), dim3(256), 0, stream>>>(img, cap, Xhi, Yhi, x2, y2, out);
  mcsc_main<<<dim3(1024), dim3(256), 0, stream>>>(Xhi, Yhi, x2, y2, nsp, shp, out);
}

// Round 5
// 138.795 us; speedup vs baseline: 1.6160x; 1.2187x over previous
//
#include <hip/hip_runtime.h>
#include <hip/hip_bf16.h>
#include <cstdint>

// MCSoftContrastiveLoss, MI355X (gfx950)
// loss = 2 * sum_{i,j} [ log(256) - log( sum_{k,l} sigmoid(2*m_ij*logit) ) ]
//   logit = shift - ns * sqrt(max(x2+y2-2xy,0)+1e-6),  m_ij = +1 if i==j else -1
// xy via single bf16 GEMM (absmax 0.0 verified R4). R5: LDS double-buffer +
// block-level reduce before atomic + barrier-free prep.

using f32x4 = __attribute__((ext_vector_type(4))) float;
using s16x8 = __attribute__((ext_vector_type(8))) short;

#define DDIM   1024
#define BM     128
#define BN     128
#define BK     64
#define LOGKK  5.5451774444795625f
#define DEPS   1e-6f

__device__ __forceinline__ void gload16(const void* g, void* l) {
  __builtin_amdgcn_global_load_lds((const __attribute__((address_space(1))) void*)g,
                                   (__attribute__((address_space(3))) void*)l, 16, 0, 0);
}

__device__ __forceinline__ unsigned short bf16_rne(float x) {
  uint32_t u = __builtin_bit_cast(uint32_t, x);
  uint32_t r = (u + 0x7FFFu + ((u >> 16) & 1u)) >> 16;
  return (unsigned short)r;
}

// -------- prep: 1 wave per row, no barriers, coalesced --------
__global__ __launch_bounds__(256) void mcsc_prep(
    const float* __restrict__ img, const float* __restrict__ cap,
    unsigned short* __restrict__ Xhi, unsigned short* __restrict__ Yhi,
    float* __restrict__ x2, float* __restrict__ y2, float* __restrict__ out)
{
  int w = blockIdx.x * 4 + (threadIdx.x >> 6);   // 0..8191
  int lane = threadIdx.x & 63;
  int isY = w >> 12;
  int row = w & 4095;
  const float* src = (isY ? cap : img) + (size_t)row * DDIM;
  unsigned short* dst = (isY ? Yhi : Xhi) + (size_t)row * DDIM;

  float s = 0.f;
#pragma unroll
  for (int j = 0; j < 4; ++j) {
    int col = (j * 64 + lane) * 4;
    float4 v = *(const float4*)(src + col);
    const float* vp = (const float*)&v;
    unsigned short h[4];
#pragma unroll
    for (int e = 0; e < 4; ++e) { float x = vp[e]; s += x * x; h[e] = bf16_rne(x); }
    *(ushort4*)(dst + col) = make_ushort4(h[0], h[1], h[2], h[3]);
  }
#pragma unroll
  for (int off = 32; off >= 1; off >>= 1) s += __shfl_xor(s, off);
  if (lane == 0) (isY ? y2 : x2)[row] = s;
  if (w == 0 && lane == 0) out[0] = 0.f;
}

// -------- main: 128x128 NT-GEMM, double-buffered LDS, fused epilogue --------
__global__ __launch_bounds__(256, 2) void mcsc_main(
    const unsigned short* __restrict__ Xhi, const unsigned short* __restrict__ Yhi,
    const float* __restrict__ x2, const float* __restrict__ y2,
    const float* __restrict__ nsp, const float* __restrict__ shp,
    float* __restrict__ out)
{
  __shared__ __align__(16) char ldsA[2][BM * BK * 2];  // 2 x 16 KiB
  __shared__ __align__(16) char ldsB[2][BN * BK * 2];  // 2 x 16 KiB
  __shared__ float redBuf[4];

  // XCD-bijective swizzle (1024 % 8 == 0)
  int bid = blockIdx.x;
  int wg = (bid & 7) * 128 + (bid >> 3);
  int bm = wg >> 5, bn = wg & 31;
  int rowBase = bm * BM, colBase = bn * BN;

  int t = threadIdx.x;
  int wid = t >> 6, lane = t & 63;
  int lr = lane & 15, lk = lane >> 4;
  int wr = wid >> 1, wc = wid & 1;
  int waveRow = wr * 64, waveCol = wc * 64;

  f32x4 acc[4][4] = {};

  // stage K-tile ks into buffer b (linear LDS dest, inverse-swizzled source)
  auto stage = [&](int ks, int b) {
    int koff = ks * BK;
#pragma unroll
    for (int c = 0; c < 4; ++c) {
      int q = c * 4096 + t * 16;               // physical LDS byte
      int row = q >> 7;                        // 128 B per tile row
      int colb = (q ^ ((row & 7) << 4)) & 127; // logical column byte
      const char* gA = (const char*)(Xhi + (size_t)(rowBase + row) * DDIM + koff) + colb;
      const char* gB = (const char*)(Yhi + (size_t)(colBase + row) * DDIM + koff) + colb;
      gload16(gA, &ldsA[b][0] + c * 4096 + wid * 1024);
      gload16(gB, &ldsB[b][0] + c * 4096 + wid * 1024);
    }
  };

  stage(0, 0);
  __syncthreads();                             // drain prologue stage

  for (int ks = 0; ks < 16; ++ks) {
    int cur = ks & 1;
    if (ks < 15) stage(ks + 1, cur ^ 1);       // issue next tile early

#pragma unroll
    for (int kk = 0; kk < BK; kk += 32) {
      s16x8 af[4], bf[4];
#pragma unroll
      for (int m = 0; m < 4; ++m) {
        int rl = waveRow + m * 16 + lr;
        int addr = rl * 128 + ((((kk + lk * 8) * 2)) ^ ((rl & 7) << 4));
        af[m] = *(const s16x8*)(&ldsA[cur][0] + addr);
      }
#pragma unroll
      for (int n = 0; n < 4; ++n) {
        int rl = waveCol + n * 16 + lr;
        int addr = rl * 128 + ((((kk + lk * 8) * 2)) ^ ((rl & 7) << 4));
        bf[n] = *(const s16x8*)(&ldsB[cur][0] + addr);
      }
#pragma unroll
      for (int m = 0; m < 4; ++m)
#pragma unroll
        for (int n = 0; n < 4; ++n)
          acc[m][n] = __builtin_amdgcn_mfma_f32_16x16x32_bf16(af[m], bf[n], acc[m][n], 0, 0, 0);
    }
    __syncthreads();   // vmcnt(0): next-tile loads (issued pre-MFMA) now drained
  }

  // fused epilogue: each 16x16 C-fragment == one (i,j) pair block
  float ns = nsp[0], sh = shp[0];
  float waveAcc = 0.f;
#pragma unroll
  for (int m = 0; m < 4; ++m) {
    int gr0 = rowBase + waveRow + m * 16;
    f32x4 x2v = *(const f32x4*)(x2 + gr0 + lk * 4);   // rows lk*4..lk*4+3
#pragma unroll
    for (int n = 0; n < 4; ++n) {
      int gc0 = colBase + waveCol + n * 16;
      bool diag = ((gr0 >> 4) == (gc0 >> 4));
      float y2c = y2[gc0 + lr];                        // col = lane&15
      float ts = 0.f;
#pragma unroll
      for (int r = 0; r < 4; ++r) {
        float sq = x2v[r] + y2c - 2.f * acc[m][n][r];
        sq = fmaxf(sq, 0.f);
        float dd = __fsqrt_rn(sq + DEPS);
        float l = sh - ns * dd;
        float a = diag ? (2.f * l) : (-2.f * l);
        ts += 1.f / (1.f + __expf(-a));                // sigmoid(2*m*l)
      }
#pragma unroll
      for (int off = 32; off >= 1; off >>= 1) ts += __shfl_xor(ts, off);
      waveAcc += (LOGKK - __logf(ts));
    }
  }
  // block-level reduce: 4 waves -> 1 atomic (atomic contention /4)
  if (lane == 0) redBuf[wid] = waveAcc;
  __syncthreads();
  if (t == 0) {
    float bs = redBuf[0] + redBuf[1] + redBuf[2] + redBuf[3];
    atomicAdd(out, 2.f * bs);
  }
}

// ---------------- launch ----------------
extern "C" void kernel_launch(void* const* d_in, const int* in_sizes, int n_in,
                              void* d_out, int out_size, void* d_ws, size_t ws_size,
                              hipStream_t stream) {
  const float* img = (const float*)d_in[0];
  const float* cap = (const float*)d_in[1];
  const float* nsp = (const float*)d_in[4];
  const float* shp = (const float*)d_in[5];
  float* out = (float*)d_out;

  char* ws = (char*)d_ws;
  unsigned short* Xhi = (unsigned short*)(ws + (size_t)0);
  unsigned short* Yhi = (unsigned short*)(ws + (size_t)8 * 1024 * 1024);
  float* x2 = (float*)(ws + (size_t)16 * 1024 * 1024);
  float* y2 = (float*)(ws + (size_t)16 * 1024 * 1024 + 16384);
  // ws needed: 16 MiB + 32 KiB

  mcsc_prep<<<dim3(2048), dim3(256), 0, stream>>>(img, cap, Xhi, Yhi, x2, y2, out);
  mcsc_main<<<dim3(1024), dim3(256), 0, stream>>>(Xhi, Yhi, x2, y2, nsp, shp, out);
}

// Round 8
// 133.198 us; speedup vs baseline: 1.6839x; 1.0420x over previous
//
#include <hip/hip_runtime.h>
#include <hip/hip_bf16.h>
#include <cstdint>

// MCSoftContrastiveLoss, MI355X (gfx950)
// loss = 2 * sum_{i,j} [ log(256) - log( sum_{k,l} sigmoid(2*m_ij*logit) ) ]
//   logit = shift - ns * sqrt(max(x2+y2-2xy,0)+1e-6),  m_ij = +1 if i==j else -1
// R6: 256x256 tile, 8 waves, 2-phase dbuf (verified sync structure from R5),
// fused epilogue. Single bf16 GEMM (absmax 0.0 verified R4/R5).

using f32x4 = __attribute__((ext_vector_type(4))) float;
using s16x8 = __attribute__((ext_vector_type(8))) short;

#define DDIM   1024
#define BM     256
#define BN     256
#define BK     64
#define LOGKK  5.5451774444795625f
#define DEPS   1e-6f

__device__ __forceinline__ void gload16(const void* g, void* l) {
  __builtin_amdgcn_global_load_lds((const __attribute__((address_space(1))) void*)g,
                                   (__attribute__((address_space(3))) void*)l, 16, 0, 0);
}

__device__ __forceinline__ unsigned short bf16_rne(float x) {
  uint32_t u = __builtin_bit_cast(uint32_t, x);
  uint32_t r = (u + 0x7FFFu + ((u >> 16) & 1u)) >> 16;
  return (unsigned short)r;
}

// -------- prep: 1 wave per row, no barriers, coalesced (R5-verified) --------
__global__ __launch_bounds__(256) void mcsc_prep(
    const float* __restrict__ img, const float* __restrict__ cap,
    unsigned short* __restrict__ Xhi, unsigned short* __restrict__ Yhi,
    float* __restrict__ x2, float* __restrict__ y2, float* __restrict__ out)
{
  int w = blockIdx.x * 4 + (threadIdx.x >> 6);   // 0..8191
  int lane = threadIdx.x & 63;
  int isY = w >> 12;
  int row = w & 4095;
  const float* src = (isY ? cap : img) + (size_t)row * DDIM;
  unsigned short* dst = (isY ? Yhi : Xhi) + (size_t)row * DDIM;

  float s = 0.f;
#pragma unroll
  for (int j = 0; j < 4; ++j) {
    int col = (j * 64 + lane) * 4;
    float4 v = *(const float4*)(src + col);
    const float* vp = (const float*)&v;
    unsigned short h[4];
#pragma unroll
    for (int e = 0; e < 4; ++e) { float x = vp[e]; s += x * x; h[e] = bf16_rne(x); }
    *(ushort4*)(dst + col) = make_ushort4(h[0], h[1], h[2], h[3]);
  }
#pragma unroll
  for (int off = 32; off >= 1; off >>= 1) s += __shfl_xor(s, off);
  if (lane == 0) (isY ? y2 : x2)[row] = s;
  if (w == 0 && lane == 0) out[0] = 0.f;
}

// -------- main: 256x256 NT-GEMM, 8 waves, 2-phase dbuf, fused epilogue --------
__global__ __launch_bounds__(512, 2) void mcsc_main(
    const unsigned short* __restrict__ Xhi, const unsigned short* __restrict__ Yhi,
    const float* __restrict__ x2, const float* __restrict__ y2,
    const float* __restrict__ nsp, const float* __restrict__ shp,
    float* __restrict__ out)
{
  // [0,64K) = A dbuf (2 x 32K), [64K,128K) = B dbuf (2 x 32K)
  __shared__ __align__(16) char lds[131072];
  __shared__ float redBuf[8];

  // XCD-bijective swizzle (256 % 8 == 0)
  int bid = blockIdx.x;
  int wg = (bid & 7) * 32 + (bid >> 3);
  int bm = wg >> 4, bn = wg & 15;                 // 16 x 16 tile grid
  int rowBase = bm * BM, colBase = bn * BN;

  int t = threadIdx.x;
  int wid = t >> 6, lane = t & 63;
  int lr = lane & 15, lk = lane >> 4;
  int wr = wid >> 2, wc = wid & 3;                // 2M x 4N waves
  int waveRow = wr * 128, waveCol = wc * 64;

  f32x4 acc[8][4] = {};

  // Staging geometry: LDS tile [256][64] bf16 row-major (128 B rows), XOR
  // swizzle byte ^= ((row&7)<<4). Thread (wid,lane), chunk c fills physical
  // byte q = c*8192 + wid*1024 + lane*16 -> row = c*64 + wid*8 + (lane>>3),
  // in-row byte (lane&7)*16; pre-swizzled source col = ((lane&7)^(lane>>3))*16.
  int srow = wid * 8 + (lane >> 3);
  int scol = (((lane & 7) ^ (lane >> 3)) * 16);
  const char* aPtr[4];
  const char* bPtr[4];
#pragma unroll
  for (int c = 0; c < 4; ++c) {
    aPtr[c] = (const char*)(Xhi + (size_t)(rowBase + c * 64 + srow) * DDIM) + scol;
    bPtr[c] = (const char*)(Yhi + (size_t)(colBase + c * 64 + srow) * DDIM) + scol;
  }
  int ldsDst = wid * 1024;                        // wave-uniform within chunk

  auto stage = [&](int ks, int b) {
    int ko = ks * 128;                            // 64 bf16 = 128 B per K-step
#pragma unroll
    for (int c = 0; c < 4; ++c) {
      gload16(aPtr[c] + ko, lds + b * 32768 + c * 8192 + ldsDst);
      gload16(bPtr[c] + ko, lds + 65536 + b * 32768 + c * 8192 + ldsDst);
    }
  };

  stage(0, 0);
  __syncthreads();                                // drain prologue stage

  for (int ks = 0; ks < 16; ++ks) {
    int cur = ks & 1;
    if (ks < 15) stage(ks + 1, cur ^ 1);          // issue next tile early

    const char* ldsA = lds + cur * 32768;
    const char* ldsB = lds + 65536 + cur * 32768;
    int swz = (lr & 7) << 4;                      // rl&7 == lr&7 (frags 16-aligned)
#pragma unroll
    for (int kk = 0; kk < BK; kk += 32) {
      int kb = (kk + lk * 8) * 2;                 // k-slice byte col
      s16x8 af[8], bf[4];
#pragma unroll
      for (int m = 0; m < 8; ++m) {
        int rl = waveRow + m * 16 + lr;
        af[m] = *(const s16x8*)(ldsA + rl * 128 + (kb ^ swz));
      }
#pragma unroll
      for (int n = 0; n < 4; ++n) {
        int rl = waveCol + n * 16 + lr;
        bf[n] = *(const s16x8*)(ldsB + rl * 128 + (kb ^ swz));
      }
#pragma unroll
      for (int m = 0; m < 8; ++m)
#pragma unroll
        for (int n = 0; n < 4; ++n)
          acc[m][n] = __builtin_amdgcn_mfma_f32_16x16x32_bf16(af[m], bf[n], acc[m][n], 0, 0, 0);
    }
    __syncthreads();   // all waves done reading cur; next iter restages cur
  }

  // fused epilogue: each 16x16 C-fragment == one (i,j) pair block
  float ns = nsp[0], sh = shp[0];
  float waveAcc = 0.f;
#pragma unroll
  for (int m = 0; m < 8; ++m) {
    int gr0 = rowBase + waveRow + m * 16;
    f32x4 x2v = *(const f32x4*)(x2 + gr0 + lk * 4);   // rows lk*4..lk*4+3
#pragma unroll
    for (int n = 0; n < 4; ++n) {
      int gc0 = colBase + waveCol + n * 16;
      bool diag = ((gr0 >> 4) == (gc0 >> 4));
      float y2c = y2[gc0 + lr];                        // col = lane&15
      float ts = 0.f;
#pragma unroll
      for (int r = 0; r < 4; ++r) {
        float sq = x2v[r] + y2c - 2.f * acc[m][n][r];
        sq = fmaxf(sq, 0.f);
        float dd = __fsqrt_rn(sq + DEPS);
        float l = sh - ns * dd;
        float a = diag ? (2.f * l) : (-2.f * l);
        ts += 1.f / (1.f + __expf(-a));                // sigmoid(2*m*l)
      }
#pragma unroll
      for (int off = 32; off >= 1; off >>= 1) ts += __shfl_xor(ts, off);
      waveAcc += (LOGKK - __logf(ts));
    }
  }
  // block-level reduce: 8 waves -> 1 atomic
  if (lane == 0) redBuf[wid] = waveAcc;
  __syncthreads();
  if (t == 0) {
    float bs = redBuf[0] + redBuf[1] + redBuf[2] + redBuf[3]
             + redBuf[4] + redBuf[5] + redBuf[6] + redBuf[7];
    atomicAdd(out, 2.f * bs);
  }
}

// ---------------- launch ----------------
extern "C" void kernel_launch(void* const* d_in, const int* in_sizes, int n_in,
                              void* d_out, int out_size, void* d_ws, size_t ws_size,
                              hipStream_t stream) {
  const float* img = (const float*)d_in[0];
  const float* cap = (const float*)d_in[1];
  const float* nsp = (const float*)d_in[4];
  const float* shp = (const float*)d_in[5];
  float* out = (float*)d_out;

  char* ws = (char*)d_ws;
  unsigned short* Xhi = (unsigned short*)(ws + (size_t)0);
  unsigned short* Yhi = (unsigned short*)(ws + (size_t)8 * 1024 * 1024);
  float* x2 = (float*)(ws + (size_t)16 * 1024 * 1024);
  float* y2 = (float*)(ws + (size_t)16 * 1024 * 1024 + 16384);
  // ws needed: 16 MiB + 32 KiB

  mcsc_prep<<<dim3(2048), dim3(256), 0, stream>>>(img, cap, Xhi, Yhi, x2, y2, out);
  mcsc_main<<<dim3(256), dim3(512), 0, stream>>>(Xhi, Yhi, x2, y2, nsp, shp, out);
}